// Round 5
// baseline (404.559 us; speedup 1.0000x reference)
//
#include <hip/hip_runtime.h>
#include <hip/hip_bf16.h>
#include <math.h>

// ---------------- types ----------------
typedef short s16x8 __attribute__((ext_vector_type(8)));
typedef float f32x4 __attribute__((ext_vector_type(4)));

// ---------------- fp32 <-> bf16 ----------------
__device__ inline unsigned short f2bf(float x) {
    unsigned int u = __float_as_uint(x);
    unsigned int r = (u + 0x7fffu + ((u >> 16) & 1u)) >> 16;
    return (unsigned short)r;
}
__device__ inline float bf2f(unsigned short u) {
    return __uint_as_float(((unsigned int)u) << 16);
}

// fast tanh: 1 - 2/(exp(2x)+1); saturates correctly at +-inf
__device__ inline float fast_tanh(float x) {
    float e = __expf(2.0f * x);
    return 1.0f - 2.0f * __builtin_amdgcn_rcpf(e + 1.0f);
}

// ---------------- fused: cvt x, cvt W_ih, pack W_lin -> bf16 [16][2336] ------
__global__ void cvtprep_kernel(const float* __restrict__ x,
                               const float* __restrict__ W_ih,
                               const float* __restrict__ W_lin,
                               unsigned short* __restrict__ xb,
                               unsigned short* __restrict__ wb,
                               unsigned short* __restrict__ wlb) {
    int blk = blockIdx.x;
    int tid = threadIdx.x;
    if (blk < 16384) {
        int i = blk * 256 + tid;
        float4 v = ((const float4*)x)[i];
        ushort4 o; o.x = f2bf(v.x); o.y = f2bf(v.y); o.z = f2bf(v.z); o.w = f2bf(v.w);
        ((ushort4*)xb)[i] = o;
    } else if (blk < 20480) {
        int i = (blk - 16384) * 256 + tid;
        float4 v = ((const float4*)W_ih)[i];
        ushort4 o; o.x = f2bf(v.x); o.y = f2bf(v.y); o.z = f2bf(v.z); o.w = f2bf(v.w);
        ((ushort4*)wb)[i] = o;
    } else {
        int idx = (blk - 20480) * 256 + tid;   // 16*2336 = 37376
        if (idx < 37376) {
            int c = idx / 2336, k = idx - c * 2336;
            float v = (c < 10 && k < 2318) ? W_lin[c * 2318 + k] : 0.f;
            wlb[idx] = f2bf(v);
        }
    }
}

// ---------------- GEMM: Hb = bf16(tanh(x @ W_ih^T + b)) ----------------
// BK=32, 128x128 tile, 256 thr (2x2 waves of 64x64), 16x16x32 MFMA.
// LDS 16B-chunk swizzle slot = c ^ ((r>>1)&3): conflict-free (validated: 0).
__global__ __launch_bounds__(256) void gemm_tanh_kernel(
    const unsigned short* __restrict__ A, const unsigned short* __restrict__ Bm,
    const float* __restrict__ b_ih, const float* __restrict__ b_hh,
    unsigned short* __restrict__ Hb)
{
    __shared__ unsigned short As[128 * 32];  // 8 KB
    __shared__ unsigned short Bs[128 * 32];  // 8 KB

    const int tid  = threadIdx.x;
    const int lane = tid & 63;
    const int wave = tid >> 6;
    const int row0 = blockIdx.x * 128;
    const int col0 = blockIdx.y * 128;
    const int wr = (wave >> 1) * 64;
    const int wc = (wave & 1) * 64;
    const int quad = lane >> 4;
    const int mrow = lane & 15;

    f32x4 acc[4][4];
#pragma unroll
    for (int i = 0; i < 4; ++i)
#pragma unroll
        for (int j = 0; j < 4; ++j)
            acc[i][j] = f32x4{0.f, 0.f, 0.f, 0.f};

    for (int k0 = 0; k0 < 2048; k0 += 32) {
        __syncthreads();
#pragma unroll
        for (int i = 0; i < 2; ++i) {
            int t = i * 256 + tid;
            int r = t >> 2, c = t & 3;
            int cg = c ^ ((r >> 1) & 3);
            const unsigned short* gp = A + (size_t)(row0 + r) * 2048 + k0 + cg * 8;
            __builtin_amdgcn_global_load_lds(
                (const __attribute__((address_space(1))) void*)gp,
                (__attribute__((address_space(3))) void*)(&As[t * 8]), 16, 0, 0);
        }
#pragma unroll
        for (int i = 0; i < 2; ++i) {
            int t = i * 256 + tid;
            int r = t >> 2, c = t & 3;
            int cg = c ^ ((r >> 1) & 3);
            const unsigned short* gp = Bm + (size_t)(col0 + r) * 2048 + k0 + cg * 8;
            __builtin_amdgcn_global_load_lds(
                (const __attribute__((address_space(1))) void*)gp,
                (__attribute__((address_space(3))) void*)(&Bs[t * 8]), 16, 0, 0);
        }
        __syncthreads();

        s16x8 af[4], bfr[4];
#pragma unroll
        for (int i = 0; i < 4; ++i) {
            int R = wr + i * 16 + mrow;
            int slot = quad ^ ((R >> 1) & 3);
            af[i] = *(const s16x8*)(&As[R * 32 + slot * 8]);
        }
#pragma unroll
        for (int j = 0; j < 4; ++j) {
            int R = wc + j * 16 + mrow;
            int slot = quad ^ ((R >> 1) & 3);
            bfr[j] = *(const s16x8*)(&Bs[R * 32 + slot * 8]);
        }
#pragma unroll
        for (int i = 0; i < 4; ++i)
#pragma unroll
            for (int j = 0; j < 4; ++j)
                acc[i][j] = __builtin_amdgcn_mfma_f32_16x16x32_bf16(
                    af[i], bfr[j], acc[i][j], 0, 0, 0);
    }

    float bias[4];
#pragma unroll
    for (int j = 0; j < 4; ++j) {
        int gc = col0 + wc + j * 16 + mrow;
        bias[j] = b_ih[gc] + b_hh[gc];
    }
#pragma unroll
    for (int i = 0; i < 4; ++i) {
#pragma unroll
        for (int r = 0; r < 4; ++r) {
            int grow = row0 + wr + i * 16 + quad * 4 + r;
#pragma unroll
            for (int j = 0; j < 4; ++j) {
                int gc = col0 + wc + j * 16 + mrow;
                float v = acc[i][j][r] + bias[j];
                Hb[(size_t)grow * 2048 + gc] = f2bf(fast_tanh(v));
            }
        }
    }
}

// ---------------- fused pool + prefix scan + windowed mean/var ----------------
// 45 blocks, one per feature. Block f reads its own 45-col stripe of Hb
// (8 threads/row cooperative uint loads + shfl reduce), pools into padded LDS,
// then runs the two-phase prefix scan and writes est_t coalesced.
// est_t layout: est_t[d*8192 + b], d = f*6 + j*2 + {0:mean,1:var}.
#define PIDX(b) ((b) + ((b) >> 5))
__global__ __launch_bounds__(256) void poolscan_kernel(
    const unsigned short* __restrict__ Hb, float* __restrict__ est_t) {
    __shared__ float pooled[8448];   // 33.8 KB (padded)
    __shared__ float sh[8448];       // 33.8 KB (padded prefix)
    __shared__ float tpart[256];
    int f = blockIdx.x;
    int tid = threadIdx.x;
    int sub = tid & 7, rgrp = tid >> 3;
    int cbeg = f * 45, cend = cbeg + 45;
    int u0 = (cbeg >> 1) + sub * 3;           // uint index into row; 24 uints cover 48 shorts >= 46 needed
    for (int r0 = 0; r0 < 8192; r0 += 32) {
        int row = r0 + rgrp;
        const unsigned int* rp = (const unsigned int*)(Hb + (size_t)row * 2048);
        float s = 0.f;
#pragma unroll
        for (int uu = 0; uu < 3; ++uu) {
            unsigned int w = rp[u0 + uu];
            int c0 = (u0 + uu) * 2;
            float v0 = bf2f((unsigned short)(w & 0xffffu));
            float v1 = bf2f((unsigned short)(w >> 16));
            s += (c0 >= cbeg && c0 < cend) ? v0 : 0.f;
            s += (c0 + 1 >= cbeg && c0 + 1 < cend) ? v1 : 0.f;
        }
        s += __shfl_down(s, 4);
        s += __shfl_down(s, 2);
        s += __shfl_down(s, 1);
        if (sub == 0) pooled[PIDX(row)] = s * (1.0f / 45.0f);
    }
    __syncthreads();

    int base = tid * 32;
#pragma unroll 1
    for (int phase = 0; phase < 2; ++phase) {
        float loc[32];
        float s = 0.f;
#pragma unroll
        for (int i = 0; i < 32; ++i) {
            float v = pooled[PIDX(base + i)];
            if (phase) v *= v;
            loc[i] = v; s += v;
        }
        tpart[tid] = s;
        __syncthreads();
        for (int d = 1; d < 256; d <<= 1) {
            float a = (tid >= d) ? tpart[tid - d] : 0.f;
            __syncthreads();
            tpart[tid] += a;
            __syncthreads();
        }
        float run = tpart[tid] - s;
#pragma unroll
        for (int i = 0; i < 32; ++i) { run += loc[i]; sh[PIDX(base + i)] = run; }
        __syncthreads();
        for (int b = tid; b < 8192; b += 256) {
            float a = sh[PIDX(b)];
#pragma unroll
            for (int j = 0; j < 3; ++j) {
                int L = (j == 0) ? 32 : (j == 1) ? 128 : 512;
                float pv = (b >= L) ? sh[PIDX(b - L)] : 0.f;
                float cnt = (float)((b + 1 < L) ? (b + 1) : L);
                int d0 = f * 6 + j * 2;
                float w = (a - pv) / cnt;
                if (phase == 0) {
                    est_t[(size_t)d0 * 8192 + b] = w;
                } else {
                    float m = est_t[(size_t)d0 * 8192 + b];   // same-thread RAW
                    est_t[(size_t)(d0 + 1) * 8192 + b] = w - m * m;
                }
            }
        }
        __syncthreads();
    }
}

// ---------------- final: MFMA GEMM [Hb|est](8192x2336) @ Wb^T(16x2336) -------
// 32 rows/block, 256 blocks. Waves: tile t = wave>>1 (16 rows), khalf = wave&1.
#define ESTRIDE 290
__global__ __launch_bounds__(256) void final_kernel(
    const unsigned short* __restrict__ Hb, const float* __restrict__ est_t,
    const unsigned short* __restrict__ Wb, const float* __restrict__ b_lin,
    float* __restrict__ out) {
    __shared__ unsigned short Es[32 * ESTRIDE];  // 18.1 KB
    __shared__ float comb[2 * 16 * 17];          // 2.1 KB
    int tid = threadIdx.x;
    int lane = tid & 63;
    int wave = tid >> 6;
    int b0 = blockIdx.x * 32;

    for (int i = tid; i < 270 * 32; i += 256) {
        int d = i >> 5, r = i & 31;
        Es[r * ESTRIDE + d] = f2bf(est_t[(size_t)d * 8192 + b0 + r]);
    }
    for (int i = tid; i < 32 * 18; i += 256) {
        int r = i / 18, d = 270 + i % 18;
        Es[r * ESTRIDE + d] = 0;
    }
    __syncthreads();

    const int t = wave >> 1;
    const int kh = wave & 1;
    const int quad = lane >> 4;
    const int mrow = lane & 15;
    const int rowt = b0 + t * 16;

    f32x4 acc = f32x4{0.f, 0.f, 0.f, 0.f};
    const unsigned short* arow = Hb + (size_t)(rowt + mrow) * 2048 + kh * 1024 + quad * 8;
    const unsigned short* brow = Wb + (size_t)mrow * 2336 + kh * 1024 + quad * 8;
#pragma unroll 4
    for (int k = 0; k < 1024; k += 32) {
        s16x8 a = *(const s16x8*)(arow + k);
        s16x8 b = *(const s16x8*)(brow + k);
        acc = __builtin_amdgcn_mfma_f32_16x16x32_bf16(a, b, acc, 0, 0, 0);
    }
    if (kh) {
        const unsigned short* erow = Es + (t * 16 + mrow) * ESTRIDE + quad * 8;
        const unsigned short* wrow = Wb + (size_t)mrow * 2336 + 2048 + quad * 8;
#pragma unroll
        for (int k = 0; k < 288; k += 32) {
            s16x8 a = *(const s16x8*)(erow + k);
            s16x8 b = *(const s16x8*)(wrow + k);
            acc = __builtin_amdgcn_mfma_f32_16x16x32_bf16(a, b, acc, 0, 0, 0);
        }
    }

    float* cb = comb + t * 272;
    if (kh == 0) {
#pragma unroll
        for (int r = 0; r < 4; ++r) cb[(quad * 4 + r) * 17 + mrow] = acc[r];
    }
    __syncthreads();
    if (kh == 1) {
#pragma unroll
        for (int r = 0; r < 4; ++r) cb[(quad * 4 + r) * 17 + mrow] += acc[r];
    }
    __syncthreads();

    if (tid < 32) {
        const float* base = comb + (tid >> 4) * 272 + (tid & 15) * 17;
        float lg[10];
        float mx = -1e30f;
#pragma unroll
        for (int c = 0; c < 10; ++c) {
            lg[c] = base[c] + b_lin[c];
            mx = fmaxf(mx, lg[c]);
        }
        float s = 0.f;
#pragma unroll
        for (int c = 0; c < 10; ++c) { lg[c] = expf(lg[c] - mx); s += lg[c]; }
        float inv = 1.0f / s;
#pragma unroll
        for (int c = 0; c < 10; ++c) out[(size_t)(b0 + tid) * 10 + c] = lg[c] * inv;
    }
}

// ---------------- launch ----------------
extern "C" void kernel_launch(void* const* d_in, const int* in_sizes, int n_in,
                              void* d_out, int out_size, void* d_ws, size_t ws_size,
                              hipStream_t stream) {
    const float* x     = (const float*)d_in[0];   // (8192,1,2048)
    const float* W_ih  = (const float*)d_in[1];   // (2048,2048)
    // d_in[2] = W_hh unused: h0 == 0 so the recurrent term vanishes
    const float* b_ih  = (const float*)d_in[3];
    const float* b_hh  = (const float*)d_in[4];
    const float* W_lin = (const float*)d_in[5];   // (10, 2318)
    const float* b_lin = (const float*)d_in[6];
    float* out = (float*)d_out;

    char* ws = (char*)d_ws;
    unsigned short* xb  = (unsigned short*)(ws);                 // 33554432 B
    unsigned short* wb  = (unsigned short*)(ws + 33554432);      //  8388608 B
    unsigned short* Hb  = (unsigned short*)(ws + 41943040);      // 33554432 B
    float* est_t        = (float*)(ws + 75497472);               //  8847360 B
    unsigned short* wlb = (unsigned short*)(ws + 84344832);      //    74752 B (~84.4 MB)

    cvtprep_kernel<<<20626, 256, 0, stream>>>(x, W_ih, W_lin, xb, wb, wlb);
    dim3 ggrid(64, 16);
    gemm_tanh_kernel<<<ggrid, 256, 0, stream>>>(xb, wb, b_ih, b_hh, Hb);
    poolscan_kernel<<<45, 256, 0, stream>>>(Hb, est_t);
    final_kernel<<<256, 256, 0, stream>>>(Hb, est_t, wlb, b_lin, out);
}

// Round 6
// 253.839 us; speedup vs baseline: 1.5938x; 1.5938x over previous
//
#include <hip/hip_runtime.h>
#include <hip/hip_bf16.h>
#include <math.h>

// ---------------- types ----------------
typedef short s16x8 __attribute__((ext_vector_type(8)));
typedef float f32x4 __attribute__((ext_vector_type(4)));

// ---------------- fp32 <-> bf16 ----------------
__device__ inline unsigned short f2bf(float x) {
    unsigned int u = __float_as_uint(x);
    unsigned int r = (u + 0x7fffu + ((u >> 16) & 1u)) >> 16;
    return (unsigned short)r;
}
__device__ inline float bf2f(unsigned short u) {
    return __uint_as_float(((unsigned int)u) << 16);
}

// fast tanh: 1 - 2/(exp(2x)+1); saturates correctly at +-inf
__device__ inline float fast_tanh(float x) {
    float e = __expf(2.0f * x);
    return 1.0f - 2.0f * __builtin_amdgcn_rcpf(e + 1.0f);
}

// ---------------- fused: cvt x, cvt W_ih, pack W_lin -> bf16 [16][2336] ------
__global__ void cvtprep_kernel(const float* __restrict__ x,
                               const float* __restrict__ W_ih,
                               const float* __restrict__ W_lin,
                               unsigned short* __restrict__ xb,
                               unsigned short* __restrict__ wb,
                               unsigned short* __restrict__ wlb) {
    int blk = blockIdx.x;
    int tid = threadIdx.x;
    if (blk < 16384) {
        int i = blk * 256 + tid;
        float4 v = ((const float4*)x)[i];
        ushort4 o; o.x = f2bf(v.x); o.y = f2bf(v.y); o.z = f2bf(v.z); o.w = f2bf(v.w);
        ((ushort4*)xb)[i] = o;
    } else if (blk < 20480) {
        int i = (blk - 16384) * 256 + tid;
        float4 v = ((const float4*)W_ih)[i];
        ushort4 o; o.x = f2bf(v.x); o.y = f2bf(v.y); o.z = f2bf(v.z); o.w = f2bf(v.w);
        ((ushort4*)wb)[i] = o;
    } else {
        int idx = (blk - 20480) * 256 + tid;   // 16*2336 = 37376
        if (idx < 37376) {
            int c = idx / 2336, k = idx - c * 2336;
            float v = (c < 10 && k < 2318) ? W_lin[c * 2318 + k] : 0.f;
            wlb[idx] = f2bf(v);
        }
    }
}

// ---------------- GEMM: Hb = bf16(tanh(x @ W_ih^T + b)) ----------------
// BK=32, 128x128 tile, 256 thr (2x2 waves of 64x64), 16x16x32 MFMA.
// LDS 16B-chunk swizzle slot = c ^ ((r>>1)&3): conflict-free (validated: 0).
__global__ __launch_bounds__(256) void gemm_tanh_kernel(
    const unsigned short* __restrict__ A, const unsigned short* __restrict__ Bm,
    const float* __restrict__ b_ih, const float* __restrict__ b_hh,
    unsigned short* __restrict__ Hb)
{
    __shared__ unsigned short As[128 * 32];  // 8 KB
    __shared__ unsigned short Bs[128 * 32];  // 8 KB

    const int tid  = threadIdx.x;
    const int lane = tid & 63;
    const int wave = tid >> 6;
    const int row0 = blockIdx.x * 128;
    const int col0 = blockIdx.y * 128;
    const int wr = (wave >> 1) * 64;
    const int wc = (wave & 1) * 64;
    const int quad = lane >> 4;
    const int mrow = lane & 15;

    f32x4 acc[4][4];
#pragma unroll
    for (int i = 0; i < 4; ++i)
#pragma unroll
        for (int j = 0; j < 4; ++j)
            acc[i][j] = f32x4{0.f, 0.f, 0.f, 0.f};

    for (int k0 = 0; k0 < 2048; k0 += 32) {
        __syncthreads();
#pragma unroll
        for (int i = 0; i < 2; ++i) {
            int t = i * 256 + tid;
            int r = t >> 2, c = t & 3;
            int cg = c ^ ((r >> 1) & 3);
            const unsigned short* gp = A + (size_t)(row0 + r) * 2048 + k0 + cg * 8;
            __builtin_amdgcn_global_load_lds(
                (const __attribute__((address_space(1))) void*)gp,
                (__attribute__((address_space(3))) void*)(&As[t * 8]), 16, 0, 0);
        }
#pragma unroll
        for (int i = 0; i < 2; ++i) {
            int t = i * 256 + tid;
            int r = t >> 2, c = t & 3;
            int cg = c ^ ((r >> 1) & 3);
            const unsigned short* gp = Bm + (size_t)(col0 + r) * 2048 + k0 + cg * 8;
            __builtin_amdgcn_global_load_lds(
                (const __attribute__((address_space(1))) void*)gp,
                (__attribute__((address_space(3))) void*)(&Bs[t * 8]), 16, 0, 0);
        }
        __syncthreads();

        s16x8 af[4], bfr[4];
#pragma unroll
        for (int i = 0; i < 4; ++i) {
            int R = wr + i * 16 + mrow;
            int slot = quad ^ ((R >> 1) & 3);
            af[i] = *(const s16x8*)(&As[R * 32 + slot * 8]);
        }
#pragma unroll
        for (int j = 0; j < 4; ++j) {
            int R = wc + j * 16 + mrow;
            int slot = quad ^ ((R >> 1) & 3);
            bfr[j] = *(const s16x8*)(&Bs[R * 32 + slot * 8]);
        }
#pragma unroll
        for (int i = 0; i < 4; ++i)
#pragma unroll
            for (int j = 0; j < 4; ++j)
                acc[i][j] = __builtin_amdgcn_mfma_f32_16x16x32_bf16(
                    af[i], bfr[j], acc[i][j], 0, 0, 0);
    }

    float bias[4];
#pragma unroll
    for (int j = 0; j < 4; ++j) {
        int gc = col0 + wc + j * 16 + mrow;
        bias[j] = b_ih[gc] + b_hh[gc];
    }
#pragma unroll
    for (int i = 0; i < 4; ++i) {
#pragma unroll
        for (int r = 0; r < 4; ++r) {
            int grow = row0 + wr + i * 16 + quad * 4 + r;
#pragma unroll
            for (int j = 0; j < 4; ++j) {
                int gc = col0 + wc + j * 16 + mrow;
                float v = acc[i][j][r] + bias[j];
                Hb[(size_t)grow * 2048 + gc] = f2bf(fast_tanh(v));
            }
        }
    }
}

// ---------------- AvgPool1d(k=45,s=45): 8 rows/block, coalesced f-major out --
__global__ __launch_bounds__(256) void pool_kernel(
    const unsigned short* __restrict__ Hb, float* __restrict__ pooled_t) {
    __shared__ unsigned short hs[8 * 2048];  // 32 KB
    __shared__ float outs[45 * 8];
    int b0 = blockIdx.x * 8;
    int tid = threadIdx.x;
    const ushort4* src = (const ushort4*)(Hb + (size_t)b0 * 2048);
    ushort4* dst = (ushort4*)hs;
    for (int i = tid; i < 4096; i += 256) dst[i] = src[i];
    __syncthreads();
    for (int o = tid; o < 360; o += 256) {
        int f = o % 45, r = o / 45;
        const unsigned short* row = hs + r * 2048 + f * 45;
        float s = 0.f;
#pragma unroll
        for (int k = 0; k < 45; ++k) s += bf2f(row[k]);
        outs[f * 8 + r] = s * (1.0f / 45.0f);
    }
    __syncthreads();
    for (int o = tid; o < 360; o += 256) {
        int f = o >> 3, r = o & 7;
        pooled_t[f * 8192 + b0 + r] = outs[o];
    }
}

// ---------------- per-feature dual prefix sum (sum, sum^2), single pass ------
// 45 blocks; ONLY the serial scan lives here (1.5 MB in, 3 MB out, coalesced).
// No est math, no global RAW - that moved to final_kernel (256 blocks).
__global__ __launch_bounds__(256) void scan_kernel(
    const float* __restrict__ pooled_t,
    float* __restrict__ cs_t, float* __restrict__ cs2_t) {
    __shared__ float t1[256], t2[256];
    int f = blockIdx.x;
    int tid = threadIdx.x;
    const float* p = pooled_t + f * 8192;
    int base = tid * 32;
    float loc[32];
    float s1 = 0.f, s2 = 0.f;
#pragma unroll
    for (int i = 0; i < 32; ++i) {
        float v = p[base + i];
        loc[i] = v; s1 += v; s2 += v * v;
    }
    t1[tid] = s1; t2[tid] = s2;
    __syncthreads();
    for (int d = 1; d < 256; d <<= 1) {
        float a1 = (tid >= d) ? t1[tid - d] : 0.f;
        float a2 = (tid >= d) ? t2[tid - d] : 0.f;
        __syncthreads();
        t1[tid] += a1; t2[tid] += a2;
        __syncthreads();
    }
    float r1 = t1[tid] - s1, r2 = t2[tid] - s2;  // exclusive offsets
    float* c1 = cs_t + f * 8192;
    float* c2 = cs2_t + f * 8192;
#pragma unroll
    for (int i = 0; i < 32; ++i) {
        float v = loc[i];
        r1 += v; r2 += v * v;
        c1[base + i] = r1; c2[base + i] = r2;
    }
}

// ---------------- final: MFMA GEMM [Hb|est](8192x2336) @ Wb^T(16x2336) -------
// 32 rows/block, 256 blocks. Es tile built from L2-hot cs_t/cs2_t (est math
// fully parallel here). Waves: tile t = wave>>1 (16 rows), khalf = wave&1.
#define ESTRIDE 290
__global__ __launch_bounds__(256) void final_kernel(
    const unsigned short* __restrict__ Hb,
    const float* __restrict__ cs_t, const float* __restrict__ cs2_t,
    const unsigned short* __restrict__ Wb, const float* __restrict__ b_lin,
    float* __restrict__ out) {
    __shared__ unsigned short Es[32 * ESTRIDE];  // 18.1 KB
    __shared__ float comb[2 * 16 * 17];          // 2.1 KB
    int tid = threadIdx.x;
    int lane = tid & 63;
    int wave = tid >> 6;
    int b0 = blockIdx.x * 32;

    // build est tile: (f,j,r) -> mean/var from prefix sums (all L2-hot)
    for (int i = tid; i < 135 * 32; i += 256) {
        int fj = i >> 5, r = i & 31;
        int f = fj / 3, j = fj - 3 * f;
        int b = b0 + r;
        int L = (j == 0) ? 32 : (j == 1) ? 128 : 512;
        const float* c1 = cs_t + f * 8192;
        const float* c2 = cs2_t + f * 8192;
        float a1 = c1[b], a2 = c2[b];
        float p1 = 0.f, p2 = 0.f;
        if (b >= L) { p1 = c1[b - L]; p2 = c2[b - L]; }
        float cnt = (float)((b + 1 < L) ? (b + 1) : L);
        float m = (a1 - p1) / cnt;
        float v = (a2 - p2) / cnt - m * m;
        int d0 = f * 6 + j * 2;
        Es[r * ESTRIDE + d0]     = f2bf(m);
        Es[r * ESTRIDE + d0 + 1] = f2bf(v);
    }
    // zero pad d in [270, 288)
    for (int i = tid; i < 32 * 18; i += 256) {
        int r = i / 18, d = 270 + i % 18;
        Es[r * ESTRIDE + d] = 0;
    }
    __syncthreads();

    const int t = wave >> 1;
    const int kh = wave & 1;
    const int quad = lane >> 4;
    const int mrow = lane & 15;
    const int rowt = b0 + t * 16;

    f32x4 acc = f32x4{0.f, 0.f, 0.f, 0.f};
    const unsigned short* arow = Hb + (size_t)(rowt + mrow) * 2048 + kh * 1024 + quad * 8;
    const unsigned short* brow = Wb + (size_t)mrow * 2336 + kh * 1024 + quad * 8;
#pragma unroll 4
    for (int k = 0; k < 1024; k += 32) {
        s16x8 a = *(const s16x8*)(arow + k);
        s16x8 b = *(const s16x8*)(brow + k);
        acc = __builtin_amdgcn_mfma_f32_16x16x32_bf16(a, b, acc, 0, 0, 0);
    }
    if (kh) {
        const unsigned short* erow = Es + (t * 16 + mrow) * ESTRIDE + quad * 8;
        const unsigned short* wrow = Wb + (size_t)mrow * 2336 + 2048 + quad * 8;
#pragma unroll
        for (int k = 0; k < 288; k += 32) {
            s16x8 a = *(const s16x8*)(erow + k);
            s16x8 b = *(const s16x8*)(wrow + k);
            acc = __builtin_amdgcn_mfma_f32_16x16x32_bf16(a, b, acc, 0, 0, 0);
        }
    }

    float* cb = comb + t * 272;
    if (kh == 0) {
#pragma unroll
        for (int r = 0; r < 4; ++r) cb[(quad * 4 + r) * 17 + mrow] = acc[r];
    }
    __syncthreads();
    if (kh == 1) {
#pragma unroll
        for (int r = 0; r < 4; ++r) cb[(quad * 4 + r) * 17 + mrow] += acc[r];
    }
    __syncthreads();

    if (tid < 32) {
        const float* base = comb + (tid >> 4) * 272 + (tid & 15) * 17;
        float lg[10];
        float mx = -1e30f;
#pragma unroll
        for (int c = 0; c < 10; ++c) {
            lg[c] = base[c] + b_lin[c];
            mx = fmaxf(mx, lg[c]);
        }
        float s = 0.f;
#pragma unroll
        for (int c = 0; c < 10; ++c) { lg[c] = expf(lg[c] - mx); s += lg[c]; }
        float inv = 1.0f / s;
#pragma unroll
        for (int c = 0; c < 10; ++c) out[(size_t)(b0 + tid) * 10 + c] = lg[c] * inv;
    }
}

// ---------------- launch ----------------
extern "C" void kernel_launch(void* const* d_in, const int* in_sizes, int n_in,
                              void* d_out, int out_size, void* d_ws, size_t ws_size,
                              hipStream_t stream) {
    const float* x     = (const float*)d_in[0];   // (8192,1,2048)
    const float* W_ih  = (const float*)d_in[1];   // (2048,2048)
    // d_in[2] = W_hh unused: h0 == 0 so the recurrent term vanishes
    const float* b_ih  = (const float*)d_in[3];
    const float* b_hh  = (const float*)d_in[4];
    const float* W_lin = (const float*)d_in[5];   // (10, 2318)
    const float* b_lin = (const float*)d_in[6];
    float* out = (float*)d_out;

    char* ws = (char*)d_ws;
    unsigned short* xb  = (unsigned short*)(ws);                 // 33554432 B
    unsigned short* wb  = (unsigned short*)(ws + 33554432);      //  8388608 B
    unsigned short* Hb  = (unsigned short*)(ws + 41943040);      // 33554432 B
    float* pooled_t     = (float*)(ws + 75497472);               //  1474560 B
    float* cs_t         = (float*)(ws + 76972032);               //  1474560 B
    float* cs2_t        = (float*)(ws + 78446592);               //  1474560 B
    unsigned short* wlb = (unsigned short*)(ws + 79921152);      //    74752 B (~80 MB)

    cvtprep_kernel<<<20626, 256, 0, stream>>>(x, W_ih, W_lin, xb, wb, wlb);
    dim3 ggrid(64, 16);
    gemm_tanh_kernel<<<ggrid, 256, 0, stream>>>(xb, wb, b_ih, b_hh, Hb);
    pool_kernel<<<1024, 256, 0, stream>>>(Hb, pooled_t);
    scan_kernel<<<45, 256, 0, stream>>>(pooled_t, cs_t, cs2_t);
    final_kernel<<<256, 256, 0, stream>>>(Hb, cs_t, cs2_t, wlb, b_lin, out);
}